// Round 8
// baseline (464.641 us; speedup 1.0000x reference)
//
#include <hip/hip_runtime.h>
#include <hip/hip_bf16.h>
#include <cstring>

using bf16 = __hip_bfloat16;

// fast sigmoid/tanh: v_exp_f32 + v_rcp_f32, saturate correctly at +-inf, no NaN.
__device__ __forceinline__ float sigm_f(float x) {
    return __builtin_amdgcn_rcpf(1.f + __expf(-x));
}
__device__ __forceinline__ float tanh_f(float x) {
    return 1.f - 2.f * __builtin_amdgcn_rcpf(1.f + __expf(2.f * x));
}

// lane l gets value of lane l^32 (both halves), via VALU permlane32_swap.
__device__ __forceinline__ float xor32_get(float x) {
#if __has_builtin(__builtin_amdgcn_permlane32_swap)
    typedef unsigned uv2 __attribute__((ext_vector_type(2)));
    union { float f; unsigned u; } cv; cv.f = x;
    uv2 r = __builtin_amdgcn_permlane32_swap(cv.u, cv.u, false, false);
    union { unsigned u; float f; } ra, rb; ra.u = r[0]; rb.u = r[1];
    return (ra.f + rb.f) - x;     // = x[l^32] in all lanes
#else
    return __shfl_xor(x, 32);
#endif
}

// ---- problem constants ----
constexpr int NH    = 128;    // hidden
constexpr int G4    = 512;    // 4*H gates
constexpr int TSEQ  = 200;
constexpr int BBATCH= 32;
constexpr int NTGT  = 8;

// ---- subgraph caps (Poisson means: |L1|~64, |S1|~72, |L2|~580, |S2|~650) ----
constexpr int LCAP1 = 1024;
constexpr int S1CAP = LCAP1 + NTGT;
constexpr int LCAP2 = 8192;
constexpr int S2CAP = LCAP2 + S1CAP;

// ---- workspace layout (bytes) ----
constexpr size_t algn(size_t x) { return (x + 255) & ~size_t(255); }
constexpr size_t OFF_GX1  = 0;                                            // 6400*512 f32
constexpr size_t OFF_GX2  = algn(OFF_GX1  + 6400ull * G4 * 4);            // 32*512 f32
constexpr size_t OFF_DEG  = algn(OFF_GX2  + 32ull * G4 * 4);              // N i32
constexpr size_t OFF_DINV = algn(OFF_DEG  + 100000ull * 4);               // hw: 1153 f32
constexpr size_t OFF_SL1  = algn(OFF_DINV + 100000ull * 4);               // N i32
constexpr size_t OFF_SL2  = algn(OFF_SL1  + 100000ull * 4);               // N i32
constexpr size_t OFF_CNT  = algn(OFF_SL2  + 100000ull * 4);               // 16 i32
constexpr size_t OFF_L1   = algn(OFF_CNT  + 64);                          // LCAP1 int2
constexpr size_t OFF_S1   = algn(OFF_L1   + (size_t)LCAP1 * 8);           // S1CAP i32
constexpr size_t OFF_L2   = algn(OFF_S1   + (size_t)S1CAP * 4);           // LCAP2 int2
constexpr size_t OFF_S2   = algn(OFF_L2   + (size_t)LCAP2 * 8);           // S2CAP i32
constexpr size_t OFF_XW1  = algn(OFF_S2   + (size_t)S2CAP * 4);           // S2CAP*128 f32
constexpr size_t OFF_H1   = algn(OFF_XW1  + (size_t)S2CAP * NH * 4);      // S1CAP*128 f32
constexpr size_t OFF_XW2  = algn(OFF_H1   + (size_t)S1CAP * NH * 4);      // S1CAP*128 f32
constexpr size_t OFF_DVEC = algn(OFF_XW2  + (size_t)S1CAP * NH * 4);      // 1152 f32
constexpr size_t OFF_H1F  = algn(OFF_DVEC + 1152ull * 4);                 // 32*128 f32 (unused, kept)
constexpr size_t OFF_CACC = algn(OFF_H1F  + 32ull * NH * 4);              // 576 f32 (unused, kept)
constexpr size_t WS_NEEDED = OFF_CACC + 576ull * 4;

// edge_index may be staged as int64 (reference dtype) or int32. If int64,
// odd int32 words are the (all-zero) high halves. cnt[15] = sniffed flag.
__device__ __forceinline__ int edge_at(const int* ei, int E, int is64, int row, int e) {
    return is64 ? ei[(((size_t)row * E) + e) * 2] : ei[((size_t)row * E) + e];
}

__device__ __forceinline__ float dinv_of(const int* deg, int v) {
    return rsqrtf((float)deg[v] + 1.0f);
}

// ============================ GCN subgraph build ============================
__global__ void k_init(const int* ei, int* deg, int* slot1, int* slot2, int* cnt,
                       float* h1, int n, unsigned int* out, unsigned int canary) {
    int i0 = blockIdx.x * 256 + threadIdx.x;
    int gstride = gridDim.x * 256;
    if (i0 < 14) cnt[i0] = 0;
    if (i0 == 15) cnt[15] = (ei[1] == 0 && ei[3] == 0 && ei[5] == 0 && ei[7] == 0) ? 1 : 0;
    if (i0 == 16) out[0] = canary;      // diagnostic; overwritten by k_lstm2n
    for (int i = i0; i < S1CAP * NH; i += gstride) h1[i] = 0.f;
    for (int i = i0; i < n; i += gstride) { deg[i] = 0; slot1[i] = -1; slot2[i] = -1; }
}

__global__ void k_deg_l1(const int* ei, int E, int* deg, int2* l1, int* cnt) {
    int is64 = cnt[15];
    for (int e = blockIdx.x * 256 + threadIdx.x; e < E; e += gridDim.x * 256) {
        int d = edge_at(ei, E, is64, 1, e);
        if ((unsigned)d < 100000u) atomicAdd(&deg[d], 1);
        if (d <= 7000 && d >= 0 && d % 1000 == 0) {          // d in TARGET
            int s = edge_at(ei, E, is64, 0, e);
            int idx = atomicAdd(&cnt[0], 1);
            if (idx < LCAP1) l1[idx] = make_int2(s, d);
        }
    }
}

// S1 set build + S2 seeding (single block)
__global__ void k_s1(const int2* l1, int* cnt, int* slot1, int* s1list,
                     int* slot2, int* s2list) {
    __shared__ int ns1;
    if (threadIdx.x == 0) ns1 = 0;
    __syncthreads();
    int m = min(cnt[0], LCAP1);
    for (int i = threadIdx.x; i < NTGT + m; i += blockDim.x) {
        int v = (i < NTGT) ? i * 1000 : l1[i - NTGT].x;
        if ((unsigned)v >= 100000u) continue;
        int old = atomicCAS(&slot1[v], -1, -2);
        if (old == -1) {
            int idx = atomicAdd(&ns1, 1);
            if (idx < S1CAP) { s1list[idx] = v; atomicExch(&slot1[v], idx); }
        }
    }
    __syncthreads();
    int n1 = min(ns1, S1CAP);
    if (threadIdx.x == 0) cnt[1] = n1;
    for (int i = threadIdx.x; i < n1; i += blockDim.x) {
        int v = s1list[i];
        int old = atomicCAS(&slot2[v], -1, -2);
        if (old == -1) {
            int idx = atomicAdd(&cnt[2], 1);
            if (idx < S2CAP) { s2list[idx] = v; atomicExch(&slot2[v], idx); }
        }
    }
}

__global__ void k_l2(const int* ei, int E, const int* slot1,
                     int2* l2, int* cnt, int* slot2, int* s2list) {
    int is64 = cnt[15];
    for (int e = blockIdx.x * 256 + threadIdx.x; e < E; e += gridDim.x * 256) {
        int d = edge_at(ei, E, is64, 1, e);
        if ((unsigned)d >= 100000u) continue;
        if (slot1[d] >= 0) {
            int s = edge_at(ei, E, is64, 0, e);
            if ((unsigned)s >= 100000u) continue;
            int idx = atomicAdd(&cnt[3], 1);
            if (idx < LCAP2) l2[idx] = make_int2(s, d);
            int old = atomicCAS(&slot2[s], -1, -2);
            if (old == -1) {
                int j = atomicAdd(&cnt[2], 1);
                if (j < S2CAP) { s2list[j] = s; atomicExch(&slot2[s], j); }
            }
        }
    }
}

// ============================ GCN compute (fp32 inputs) ============================

__global__ void k_xw1(const float* x, const float* W, const int* s2list, const int* cnt, float* xw1) {
    int i = blockIdx.x;
    if (i >= min(cnt[2], S2CAP)) return;
    int node = s2list[i];
    __shared__ float xs[NH];
    int c = threadIdx.x;
    xs[c] = x[(size_t)node * NH + c];
    __syncthreads();
    float acc = 0.f;
    #pragma unroll 8
    for (int k = 0; k < NH; k++) acc += xs[k] * W[(size_t)k * NH + c];
    xw1[(size_t)i * NH + c] = acc;
}

__global__ void k_h1scat(const float* xw1, const int2* l2, const int* cnt,
                         const int* slot1, const int* slot2, const int* deg, float* h1) {
    int e = blockIdx.x;
    if (e >= min(cnt[3], LCAP2)) return;
    int2 sd = l2[e];
    int t1 = slot1[sd.y], s2 = slot2[sd.x];
    if (t1 < 0 || t1 >= S1CAP || s2 < 0 || s2 >= S2CAP) return;
    float w = dinv_of(deg, sd.x) * dinv_of(deg, sd.y);
    atomicAdd(&h1[t1 * NH + threadIdx.x],
              xw1[(size_t)s2 * NH + threadIdx.x] * w);
}

// self-loop base term folded in: xs = relu(h1_scatter + xw1[node]*dinv^2 + b1), then @ W2.
__global__ void k_xw2(const float* h1, const float* xw1, const float* W, const float* b1,
                      const int* cnt, const int* s1list, const int* slot2, const int* deg,
                      float* xw2) {
    int i = blockIdx.x;
    if (i >= min(cnt[1], S1CAP)) return;
    __shared__ float xs[NH];
    int c = threadIdx.x;
    int node = s1list[i];
    int s2i = slot2[node];
    if (s2i < 0 || s2i >= S2CAP) s2i = 0;
    float v = dinv_of(deg, node);
    xs[c] = fmaxf(h1[i * NH + c] + xw1[(size_t)s2i * NH + c] * (v * v) + b1[c], 0.f);
    __syncthreads();
    float acc = 0.f;
    #pragma unroll 8
    for (int k = 0; k < NH; k++) acc += xs[k] * W[(size_t)k * NH + c];
    xw2[(size_t)i * NH + c] = acc;
}

__global__ void k_gout(const float* xw2, const int2* l1, const int* cnt,
                       const int* slot1, const int* deg, const float* b2, float* dvec) {
    int t = blockIdx.x;             // 0..7
    int tgt = t * 1000;
    int c = threadIdx.x;
    float vt = dinv_of(deg, tgt);
    int st = slot1[tgt]; if (st < 0 || st >= S1CAP) st = 0;
    float acc = xw2[(size_t)st * NH + c] * vt * vt;
    int m = min(cnt[0], LCAP1);
    for (int e = 0; e < m; e++) {
        int2 sd = l1[e];
        if (sd.y == tgt) {
            int ss = slot1[sd.x];
            if (ss >= 0 && ss < S1CAP)
                acc += xw2[(size_t)ss * NH + c] * dinv_of(deg, sd.x) * vt;
        }
    }
    acc += b2[c];
    dvec[t * NH + c] = fmaxf(acc, 0.f);
}

// ============================ LSTM (fp32 inputs) ============================

// gx1 = data0_rows @ Wih1^T + bias, LDS-tiled GEMM. Blocks >= 800 instead
// compute the head weight-collapse hw = m1w@m2w (1152 f32) + hbias.
__global__ __launch_bounds__(256) void k_gx1hw(const float* data0, const float* Wih,
                                               const float* bih, const float* bhh, float* gx,
                                               const float* m1w, const float* m1b,
                                               const float* m2w, const float* m2b, float* hw) {
    int tid = threadIdx.x;
    if (blockIdx.x >= 800) {
        int hb = blockIdx.x - 800;                // 0..18
        int wv = tid >> 6, ln = tid & 63;
        if (hb < 18) {
            #pragma unroll 4
            for (int rr = 0; rr < 16; rr++) {
                int row = hb * 64 + wv * 16 + rr;
                float s = 0.f;
                #pragma unroll
                for (int j = ln; j < 576; j += 64) s += m1w[(size_t)row * 576 + j] * m2w[j];
                #pragma unroll
                for (int off = 32; off > 0; off >>= 1) s += __shfl_down(s, off, 64);
                if (ln == 0) hw[row] = s;
            }
        } else if (wv == 0) {                     // hbias = m1b@m2w + m2b
            float s = 0.f;
            for (int j = ln; j < 576; j += 64) s += m1b[j] * m2w[j];
            #pragma unroll
            for (int off = 32; off > 0; off >>= 1) s += __shfl_down(s, off, 64);
            if (ln == 0) hw[1152] = s + m2b[0];
        }
        return;
    }
    constexpr int LDP = 68;                       // pad 64->68 breaks bank conflicts
    __shared__ float As[64 * LDP];                // rows x k
    __shared__ float Bs[64 * LDP];                // gates x k
    int rb = blockIdx.x >> 3;                     // 0..99  row block
    int gb = blockIdx.x & 7;                      // 0..7   gate block
    int r0 = rb * 64, g0 = gb * 64;
    for (int i = tid; i < 64 * 64; i += 256) {
        int rr = i >> 6, k = i & 63;
        int r = r0 + rr, b = r & 31, t = r >> 5;
        As[rr * LDP + k] = data0[((size_t)b * TSEQ + t) * 64 + k];
        Bs[rr * LDP + k] = Wih[(size_t)(g0 + rr) * 64 + k];
    }
    __syncthreads();
    int tr = (tid & 15) * 4;                      // 4 rows
    int tg = (tid >> 4) * 4;                      // 4 gates
    float acc[4][4] = {};
    #pragma unroll
    for (int k4 = 0; k4 < 16; k4++) {
        float4 a0 = *(const float4*)&As[(tr + 0) * LDP + k4 * 4];
        float4 a1 = *(const float4*)&As[(tr + 1) * LDP + k4 * 4];
        float4 a2 = *(const float4*)&As[(tr + 2) * LDP + k4 * 4];
        float4 a3 = *(const float4*)&As[(tr + 3) * LDP + k4 * 4];
        float4 b0 = *(const float4*)&Bs[(tg + 0) * LDP + k4 * 4];
        float4 b1 = *(const float4*)&Bs[(tg + 1) * LDP + k4 * 4];
        float4 b2 = *(const float4*)&Bs[(tg + 2) * LDP + k4 * 4];
        float4 b3 = *(const float4*)&Bs[(tg + 3) * LDP + k4 * 4];
        const float4 av[4] = {a0, a1, a2, a3};
        const float4 bv[4] = {b0, b1, b2, b3};
        #pragma unroll
        for (int i = 0; i < 4; i++)
            #pragma unroll
            for (int j = 0; j < 4; j++)
                acc[i][j] += av[i].x * bv[j].x + av[i].y * bv[j].y
                           + av[i].z * bv[j].z + av[i].w * bv[j].w;
    }
    float bias[4];
    #pragma unroll
    for (int j = 0; j < 4; j++) bias[j] = bih[g0 + tg + j] + bhh[g0 + tg + j];
    #pragma unroll
    for (int i = 0; i < 4; i++) {
        size_t row = (size_t)(r0 + tr + i) * G4 + g0 + tg;
        #pragma unroll
        for (int j = 0; j < 4; j++) gx[row + j] = acc[i][j] + bias[j];
    }
}

// R16: full-rate f32 FMA recurrence. Hypothesis (fits ALL R0-R7 data): FDOT2
// (v_dot2 f16) issues at QUARTER rate (~8cyc/wave64) — 128/lane was 1024
// cyc/SIMD/step, the invariant ~1500cyc step. Replace with full-rate f32
// v_fma (2cyc). f32 weights: 2 rows x 64 k = 128 VGPR/lane (fits; R4: 256
// spills) => need 4 lanes per unit => 8 waves x 16 units:
//   lane l, wave w:  j = w*16 + (l&15)   unit
//                    kh = (l>>4)&1       k-half  [kh*64, kh*64+64)
//                    role = l>>5         0:{i,g} 1:{f,o}
// k-half combine: __shfl_xor(.,16) (partner same j,role). role combine:
// permlane32_swap (partner same j,kh). h kept f32 in LDS (numerics improve).
// 2 waves/SIMD (launch_bounds(512,2) caps VGPR at 256, no spill).
template<int T, int NB>
__global__ __launch_bounds__(512, 2) void k_lstm1n(const float* gx, const float* Whh,
                                                   const float* Wih2, const float* bih2,
                                                   const float* bhh2, float* gx2) {
    int b = blockIdx.x;
    int tid = threadIdx.x;
    int w = tid >> 6, l = tid & 63;
    int j = w * 16 + (l & 15);                    // hidden unit 0..127
    int kh = (l >> 4) & 1;                        // k-half
    int k0 = kh * 64;
    int role = l >> 5;                            // 0: i,g   1: f,o
    int rowA = role ? (j + NH) : j;               // f : i
    int rowB = role ? (j + 3 * NH) : (j + 2 * NH);// o : g
    __shared__ __align__(16) float hbuf[2][NH];
    __shared__ float hfin[NH];
    float wA[64], wB[64];                         // 128 f32 VGPRs
    #pragma unroll
    for (int k = 0; k < 64; k += 4) {
        float4 a = *(const float4*)&Whh[(size_t)rowA * NH + k0 + k];
        wA[k] = a.x; wA[k + 1] = a.y; wA[k + 2] = a.z; wA[k + 3] = a.w;
        float4 c4 = *(const float4*)&Whh[(size_t)rowB * NH + k0 + k];
        wB[k] = c4.x; wB[k + 1] = c4.y; wB[k + 2] = c4.z; wB[k + 3] = c4.w;
    }
    if (tid < NH) { hbuf[0][tid] = 0.f; hbuf[1][tid] = 0.f; }
    float c = 0.f, hout = 0.f;
    const float* gp0 = &gx[(size_t)b * G4];
    float nxA = gp0[rowA], nxB = gp0[rowB];
    __syncthreads();
    for (int t = 0; t < T; t++) {
        const float4* hv = (const float4*)&hbuf[t & 1][k0];
        float aA = nxA, aB = nxB;
        int tn = (t + 1 < T) ? (t + 1) : t;
        const float* gp = &gx[((size_t)tn * NB + b) * G4];  // prefetch next step
        nxA = gp[rowA]; nxB = gp[rowB];
        float pA0 = 0.f, pA1 = 0.f, pB0 = 0.f, pB1 = 0.f;
        #pragma unroll
        for (int m = 0; m < 16; m++) {                      // 128 full-rate FMA
            float4 h4 = hv[m];
            pA0 = fmaf(wA[4 * m],     h4.x, pA0);
            pA1 = fmaf(wA[4 * m + 1], h4.y, pA1);
            pA0 = fmaf(wA[4 * m + 2], h4.z, pA0);
            pA1 = fmaf(wA[4 * m + 3], h4.w, pA1);
            pB0 = fmaf(wB[4 * m],     h4.x, pB0);
            pB1 = fmaf(wB[4 * m + 1], h4.y, pB1);
            pB0 = fmaf(wB[4 * m + 2], h4.z, pB0);
            pB1 = fmaf(wB[4 * m + 3], h4.w, pB1);
        }
        float pA = pA0 + pA1, pB = pB0 + pB1;
        pA += __shfl_xor(pA, 16, 64);                       // k-half combine
        pB += __shfl_xor(pB, 16, 64);
        float gA = aA + pA;                                 // i-pre | f-pre (full)
        float gB = aB + pB;                                 // g-pre | o-pre (full)
        float s  = sigm_f(gA);                              // sigm(i) | sigm(f)
        float tg = role ? sigm_f(gB) : tanh_f(gB);          // tanh(g) | sigm(o)
        float u  = s * tg;                                  // role0: sigm(i)*tanh(g)
        float fv = xor32_get(s);                            // role0 gets sigm(f)
        float ov = xor32_get(tg);                           // role0 gets sigm(o)
        if (role == 0) {
            c = fv * c + u;
            hout = ov * tanh_f(c);
            if (kh == 0) hbuf[(t + 1) & 1][j] = hout;       // l<16 lanes write
        }
        __syncthreads();                                    // single barrier/step
    }
    if (l < 16) hfin[j] = hout;                             // role0,kh0 lanes
    __syncthreads();
    // ---- folded k_gx2: gx2[b][g] = hfin . Wih2[g] + biases (1 gate/thread) ----
    int g = tid;                                            // 512 gates
    float a0 = bih2[g] + bhh2[g];
    const float4* wp = (const float4*)&Wih2[(size_t)g * NH];
    const float4* hp = (const float4*)hfin;
    #pragma unroll 8
    for (int k4 = 0; k4 < NH / 4; k4++) {
        float4 h4 = hp[k4];
        float4 wv = wp[k4];
        a0 += wv.x * h4.x + wv.y * h4.y + wv.z * h4.z + wv.w * h4.w;
    }
    gx2[(size_t)b * G4 + g] = a0;
}

// lstm2 (T=32, NB=1, 1 block, same R16 structure) + folded head epilogue:
// out = dvec[0:1024].hw[0:1024] + h2.hw[1024:1152] + hw[1152]  (bf16 dual store)
__global__ __launch_bounds__(512, 2) void k_lstm2n(const float* gx, const float* Whh,
                                                   const float* dvec, const float* hw,
                                                   unsigned int* out) {
    constexpr int T = BBATCH;                     // 32 steps
    int tid = threadIdx.x;
    int w = tid >> 6, l = tid & 63;
    int j = w * 16 + (l & 15);
    int kh = (l >> 4) & 1;
    int k0 = kh * 64;
    int role = l >> 5;
    int rowA = role ? (j + NH) : j;
    int rowB = role ? (j + 3 * NH) : (j + 2 * NH);
    __shared__ __align__(16) float hbuf[2][NH];
    __shared__ float harr[NH];
    __shared__ float red[8];
    float wA[64], wB[64];
    #pragma unroll
    for (int k = 0; k < 64; k += 4) {
        float4 a = *(const float4*)&Whh[(size_t)rowA * NH + k0 + k];
        wA[k] = a.x; wA[k + 1] = a.y; wA[k + 2] = a.z; wA[k + 3] = a.w;
        float4 c4 = *(const float4*)&Whh[(size_t)rowB * NH + k0 + k];
        wB[k] = c4.x; wB[k + 1] = c4.y; wB[k + 2] = c4.z; wB[k + 3] = c4.w;
    }
    if (tid < NH) { hbuf[0][tid] = 0.f; hbuf[1][tid] = 0.f; }
    float c = 0.f, hout = 0.f;
    float nxA = gx[rowA], nxB = gx[rowB];
    __syncthreads();
    for (int t = 0; t < T; t++) {
        const float4* hv = (const float4*)&hbuf[t & 1][k0];
        float aA = nxA, aB = nxB;
        int tn = (t + 1 < T) ? (t + 1) : t;
        const float* gp = &gx[(size_t)tn * G4];
        nxA = gp[rowA]; nxB = gp[rowB];
        float pA0 = 0.f, pA1 = 0.f, pB0 = 0.f, pB1 = 0.f;
        #pragma unroll
        for (int m = 0; m < 16; m++) {
            float4 h4 = hv[m];
            pA0 = fmaf(wA[4 * m],     h4.x, pA0);
            pA1 = fmaf(wA[4 * m + 1], h4.y, pA1);
            pA0 = fmaf(wA[4 * m + 2], h4.z, pA0);
            pA1 = fmaf(wA[4 * m + 3], h4.w, pA1);
            pB0 = fmaf(wB[4 * m],     h4.x, pB0);
            pB1 = fmaf(wB[4 * m + 1], h4.y, pB1);
            pB0 = fmaf(wB[4 * m + 2], h4.z, pB0);
            pB1 = fmaf(wB[4 * m + 3], h4.w, pB1);
        }
        float pA = pA0 + pA1, pB = pB0 + pB1;
        pA += __shfl_xor(pA, 16, 64);
        pB += __shfl_xor(pB, 16, 64);
        float gA = aA + pA;
        float gB = aB + pB;
        float s  = sigm_f(gA);
        float tg = role ? sigm_f(gB) : tanh_f(gB);
        float u  = s * tg;
        float fv = xor32_get(s);
        float ov = xor32_get(tg);
        if (role == 0) {
            c = fv * c + u;
            hout = ov * tanh_f(c);
            if (kh == 0) hbuf[(t + 1) & 1][j] = hout;
        }
        __syncthreads();
    }
    if (l < 16) harr[j] = hout;
    __syncthreads();
    // ---- folded head: final 1152-dot against collapsed weights hw ----
    float s = 0.f;
    for (int i = tid; i < 1024; i += 512) s += dvec[i] * hw[i];
    if (tid < NH) s += harr[tid] * hw[1024 + tid];
    #pragma unroll
    for (int off = 32; off > 0; off >>= 1) s += __shfl_down(s, off, 64);
    if ((tid & 63) == 0) red[tid >> 6] = s;
    __syncthreads();
    if (tid == 0) {
        float tot = red[0] + red[1] + red[2] + red[3]
                  + red[4] + red[5] + red[6] + red[7] + hw[1152];
        bf16 hb = __float2bfloat16(tot);
        unsigned short u;
        memcpy(&u, &hb, 2);
        out[0] = ((unsigned int)u << 16) | u;
    }
}

// ============================ launcher ============================

extern "C" void kernel_launch(void* const* d_in, const int* in_sizes, int n_in,
                              void* d_out, int out_size, void* d_ws, size_t ws_size,
                              hipStream_t stream) {
    const float* data0 = (const float*)d_in[0];
    const float* data1 = (const float*)d_in[1];
    const int*   ei    = (const int*)d_in[2];
    const float* W1    = (const float*)d_in[3];
    const float* b1    = (const float*)d_in[4];
    const float* W2    = (const float*)d_in[5];
    const float* b2    = (const float*)d_in[6];
    const float* Wih1  = (const float*)d_in[7];
    const float* Whh1  = (const float*)d_in[8];
    const float* bih1  = (const float*)d_in[9];
    const float* bhh1  = (const float*)d_in[10];
    const float* Wih2  = (const float*)d_in[11];
    const float* Whh2  = (const float*)d_in[12];
    const float* bih2  = (const float*)d_in[13];
    const float* bhh2  = (const float*)d_in[14];
    const float* m1w   = (const float*)d_in[15];
    const float* m1b   = (const float*)d_in[16];
    const float* m2w   = (const float*)d_in[17];
    const float* m2b   = (const float*)d_in[18];

    const int n = in_sizes[1] / NH;       // 100000
    const int E = in_sizes[2] / 2;        // 800000 (elements; int width sniffed on device)

    char* ws = (char*)d_ws;
    float* gx1   = (float*)(ws + OFF_GX1);
    float* gx2   = (float*)(ws + OFF_GX2);
    int*   deg   = (int*)  (ws + OFF_DEG);
    float* hw    = (float*)(ws + OFF_DINV);   // 1153 f32, reuses dead region
    int*   slot1 = (int*)  (ws + OFF_SL1);
    int*   slot2 = (int*)  (ws + OFF_SL2);
    int*   cnt   = (int*)  (ws + OFF_CNT);
    int2*  l1    = (int2*) (ws + OFF_L1);
    int*   s1l   = (int*)  (ws + OFF_S1);
    int2*  l2    = (int2*) (ws + OFF_L2);
    int*   s2l   = (int*)  (ws + OFF_S2);
    float* xw1   = (float*)(ws + OFF_XW1);
    float* h1    = (float*)(ws + OFF_H1);
    float* xw2   = (float*)(ws + OFF_XW2);
    float* dvec  = (float*)(ws + OFF_DVEC);

    // diagnostic canary bits (written by k_init, overwritten by k_lstm2n)
    float v = 1.0f + (ws_size < WS_NEEDED ? 1.0f : 0.0f) + (n_in != 19 ? 2.0f : 0.0f);
    unsigned int fb; memcpy(&fb, &v, 4);
    unsigned int hi = fb >> 16;
    unsigned int canary_bits = (hi << 16) | hi;

    int nb = (n + 255) / 256;
    int eb = (E + 255) / 256;

    // subgraph build
    k_init   <<<nb, 256, 0, stream>>>(ei, deg, slot1, slot2, cnt, h1, n,
                                      (unsigned int*)d_out, canary_bits);
    k_deg_l1 <<<eb, 256, 0, stream>>>(ei, E, deg, l1, cnt);
    k_s1     <<<1, 256, 0, stream>>>(l1, cnt, slot1, s1l, slot2, s2l);
    k_l2     <<<eb, 256, 0, stream>>>(ei, E, slot1, l2, cnt, slot2, s2l);
    // GCN compute on active subgraph
    k_xw1    <<<S2CAP, NH, 0, stream>>>(data1, W1, s2l, cnt, xw1);
    k_h1scat <<<LCAP2, NH, 0, stream>>>(xw1, l2, cnt, slot1, slot2, deg, h1);
    k_xw2    <<<S1CAP, NH, 0, stream>>>(h1, xw1, W2, b1, cnt, s1l, slot2, deg, xw2);
    k_gout   <<<NTGT, NH, 0, stream>>>(xw2, l1, cnt, slot1, deg, b2, dvec);
    // LSTM path (+ head weight-collapse piggybacked on gx1's dispatch)
    k_gx1hw  <<<819, 256, 0, stream>>>(data0, Wih1, bih1, bhh1, gx1,
                                       m1w, m1b, m2w, m2b, hw);
    k_lstm1n<TSEQ, BBATCH><<<BBATCH, 512, 0, stream>>>(gx1, Whh1, Wih2, bih2, bhh2, gx2);
    k_lstm2n <<<1, 512, 0, stream>>>(gx2, Whh2, dvec, hw, (unsigned int*)d_out);
    (void)out_size;
}